// Round 1
// baseline (1094.775 us; speedup 1.0000x reference)
//
#include <hip/hip_runtime.h>
#include <hip/hip_bf16.h>
#include <cstdint>
#include <cstddef>

// ---------------- CSR build ----------------

__global__ __launch_bounds__(256) void k_count(const int* __restrict__ dst, int* __restrict__ cnt, int E) {
    int i = blockIdx.x * blockDim.x + threadIdx.x;
    int stride = gridDim.x * blockDim.x;
    for (; i < E; i += stride) atomicAdd(&cnt[dst[i]], 1);
}

__global__ __launch_bounds__(256) void k_dinv(const int* __restrict__ cnt, float* __restrict__ dinv, int N) {
    int i = blockIdx.x * blockDim.x + threadIdx.x;
    if (i < N) dinv[i] = rsqrtf((float)(cnt[i] + 1));
}

// per-block exclusive scan of (cnt[i]+1), block totals to partials
__global__ __launch_bounds__(256) void k_scan_a(const int* __restrict__ cnt, int* __restrict__ offs,
                                                int* __restrict__ partials, int N) {
    __shared__ int sh[256];
    int t = threadIdx.x;
    int i = blockIdx.x * 256 + t;
    int v = (i < N) ? (cnt[i] + 1) : 0;
    sh[t] = v;
    __syncthreads();
    for (int d = 1; d < 256; d <<= 1) {
        int add = (t >= d) ? sh[t - d] : 0;
        __syncthreads();
        sh[t] += add;
        __syncthreads();
    }
    if (i < N) offs[i] = sh[t] - v;       // exclusive within block
    if (t == 255) partials[blockIdx.x] = sh[255];
}

// single-block inclusive scan of partials (nb <= 512)
__global__ __launch_bounds__(512) void k_scan_b(int* __restrict__ partials, int nb) {
    __shared__ int sh[512];
    int t = threadIdx.x;
    int v = (t < nb) ? partials[t] : 0;
    sh[t] = v;
    __syncthreads();
    for (int d = 1; d < 512; d <<= 1) {
        int add = (t >= d) ? sh[t - d] : 0;
        __syncthreads();
        sh[t] += add;
        __syncthreads();
    }
    if (t < nb) partials[t] = sh[t];
}

__global__ __launch_bounds__(256) void k_scan_c(int* __restrict__ offs, const int* __restrict__ partials,
                                                int N, int nb) {
    int i = blockIdx.x * 256 + threadIdx.x;
    if (i < N) {
        int b = i >> 8;
        if (b > 0) offs[i] += partials[b - 1];
    } else if (i == N) {
        offs[N] = partials[nb - 1];
    }
}

__global__ __launch_bounds__(256) void k_fill(const int* __restrict__ src, const int* __restrict__ dst,
                                              const int* __restrict__ offs, int* __restrict__ cur,
                                              const float* __restrict__ dinv,
                                              int* __restrict__ csrc, float* __restrict__ cnorm, int E) {
    int i = blockIdx.x * blockDim.x + threadIdx.x;
    int stride = gridDim.x * blockDim.x;
    for (; i < E; i += stride) {
        int s = src[i], d = dst[i];
        int pos = offs[d] + atomicAdd(&cur[d], 1);
        csrc[pos] = s;
        cnorm[pos] = dinv[s] * dinv[d];
    }
}

__global__ __launch_bounds__(256) void k_fill_loops(const int* __restrict__ offs, int* __restrict__ cur,
                                                    const float* __restrict__ dinv,
                                                    int* __restrict__ csrc, float* __restrict__ cnorm, int N) {
    int i = blockIdx.x * blockDim.x + threadIdx.x;
    if (i < N) {
        int pos = offs[i] + atomicAdd(&cur[i], 1);
        csrc[pos] = i;
        float di = dinv[i];
        cnorm[pos] = di * di;
    }
}

// ---------------- node features: x = [emb[label], MLP(bbox)] ----------------

__global__ __launch_bounds__(256) void k_feat(const int* __restrict__ label, const float* __restrict__ bbox,
                                              const float* __restrict__ emb,
                                              const float* __restrict__ w1, const float* __restrict__ b1,
                                              const float* __restrict__ w2, const float* __restrict__ b2,
                                              float* __restrict__ X, int N) {
    __shared__ float w1s[4 * 64];
    __shared__ float b1s[64], b2s[64];
    __shared__ float w2s[64 * 64];
    __shared__ float h1s[4][64];
    int t = threadIdx.x;
    if (t < 256) w1s[t] = w1[t];
    if (t < 64) { b1s[t] = b1[t]; b2s[t] = b2[t]; }
    for (int i = t; i < 64 * 64; i += 256) w2s[i] = w2[i];
    __syncthreads();

    int wave = t >> 6, lane = t & 63;
    int node = blockIdx.x * 4 + wave;
    bool ok = node < N;

    float h1 = 0.f;
    if (ok) {
        float bb0 = bbox[node * 4 + 0];
        float bb1 = bbox[node * 4 + 1];
        float bb2 = bbox[node * 4 + 2];
        float bb3 = bbox[node * 4 + 3];
        h1 = bb0 * w1s[0 * 64 + lane] + bb1 * w1s[1 * 64 + lane]
           + bb2 * w1s[2 * 64 + lane] + bb3 * w1s[3 * 64 + lane] + b1s[lane];
        h1 = fmaxf(h1, 0.f);
    }
    h1s[wave][lane] = h1;
    __syncthreads();

    if (ok) {
        float acc = b2s[lane];
        #pragma unroll 8
        for (int k = 0; k < 64; ++k) acc += h1s[wave][k] * w2s[k * 64 + lane];
        int lb = label[node];
        X[(size_t)node * 128 + lane] = emb[(size_t)lb * 64 + lane];
        X[(size_t)node * 128 + 64 + lane] = acc;
    }
}

// ---------------- in-place X <- X @ W  (W is 128x128 row-major) ----------------

__global__ __launch_bounds__(256) void k_gemm128(float* __restrict__ X, const float* __restrict__ W, int N) {
    __shared__ float Xl[64 * 128];   // 32 KiB: full 64-row tile
    __shared__ float Wl[64 * 128];   // 32 KiB: half of W (64 k-rows)
    int t = threadIdx.x;
    int n0 = blockIdx.x * 64;
    int rows = N - n0; if (rows > 64) rows = 64;

    const float4* X4 = (const float4*)X;
    float4* Xl4 = (float4*)Xl;
    for (int i = t; i < rows * 32; i += 256) {
        Xl4[i] = X4[(size_t)n0 * 32 + i];
    }

    float acc[4][8];
    #pragma unroll
    for (int i = 0; i < 4; ++i)
        #pragma unroll
        for (int j = 0; j < 8; ++j) acc[i][j] = 0.f;

    int tr = t >> 4;     // 0..15 -> rows tr*4 .. tr*4+3
    int tc = t & 15;     // 0..15 -> cols tc*8 .. tc*8+7
    const float4* W4 = (const float4*)W;
    float4* Wl4 = (float4*)Wl;

    for (int kp = 0; kp < 2; ++kp) {
        __syncthreads();   // Xl ready (kp=0) / previous pass done reading Wl (kp=1)
        for (int i = t; i < 64 * 32; i += 256) Wl4[i] = W4[kp * 2048 + i];
        __syncthreads();
        #pragma unroll 16
        for (int kl = 0; kl < 64; ++kl) {
            int k = kp * 64 + kl;
            float4 w0 = Wl4[kl * 32 + tc * 2];
            float4 w1 = Wl4[kl * 32 + tc * 2 + 1];
            float xv[4];
            #pragma unroll
            for (int i = 0; i < 4; ++i) xv[i] = Xl[(tr * 4 + i) * 128 + k];
            #pragma unroll
            for (int i = 0; i < 4; ++i) {
                acc[i][0] += xv[i] * w0.x; acc[i][1] += xv[i] * w0.y;
                acc[i][2] += xv[i] * w0.z; acc[i][3] += xv[i] * w0.w;
                acc[i][4] += xv[i] * w1.x; acc[i][5] += xv[i] * w1.y;
                acc[i][6] += xv[i] * w1.z; acc[i][7] += xv[i] * w1.w;
            }
        }
    }

    #pragma unroll
    for (int i = 0; i < 4; ++i) {
        int r = tr * 4 + i;
        if (r < rows) {
            float4* out = (float4*)(X + ((size_t)(n0 + r)) * 128 + tc * 8);
            out[0] = make_float4(acc[i][0], acc[i][1], acc[i][2], acc[i][3]);
            out[1] = make_float4(acc[i][4], acc[i][5], acc[i][6], acc[i][7]);
        }
    }
}

// ---------------- aggregation: Y[n] = relu?(sum_e norm_e * H[src_e] + b) ----------------

__global__ __launch_bounds__(256) void k_agg(const float* __restrict__ H, const int* __restrict__ offs,
                                             const int* __restrict__ csrc, const float* __restrict__ cnorm,
                                             const float* __restrict__ bias, float* __restrict__ Y,
                                             int N, int do_relu) {
    int node = blockIdx.x * 2 + (threadIdx.x >> 7);
    if (node >= N) return;
    int c = threadIdx.x & 127;
    int i0 = offs[node], i1 = offs[node + 1];
    float acc = 0.f;
    int i = i0;
    for (; i + 2 <= i1; i += 2) {
        int s0 = csrc[i], s1 = csrc[i + 1];
        float w0 = cnorm[i], w1 = cnorm[i + 1];
        acc += H[(size_t)s0 * 128 + c] * w0;
        acc += H[(size_t)s1 * 128 + c] * w1;
    }
    if (i < i1) {
        acc += H[(size_t)csrc[i] * 128 + c] * cnorm[i];
    }
    acc += bias[c];
    if (do_relu) acc = fmaxf(acc, 0.f);
    Y[(size_t)node * 128 + c] = acc;
}

// ---------------- launch ----------------

extern "C" void kernel_launch(void* const* d_in, const int* in_sizes, int n_in,
                              void* d_out, int out_size, void* d_ws, size_t ws_size,
                              hipStream_t stream) {
    const int*   label = (const int*)d_in[0];
    const float* bbox  = (const float*)d_in[1];
    const int*   eidx  = (const int*)d_in[2];
    const float* emb   = (const float*)d_in[3];
    const float* w1    = (const float*)d_in[4];
    const float* b1    = (const float*)d_in[5];
    const float* w2    = (const float*)d_in[6];
    const float* b2    = (const float*)d_in[7];
    const float* wg0   = (const float*)d_in[8];
    const float* bg0   = (const float*)d_in[9];
    const float* wg1   = (const float*)d_in[10];
    const float* bg1   = (const float*)d_in[11];
    const float* wg2   = (const float*)d_in[12];
    const float* bg2   = (const float*)d_in[13];

    int N = in_sizes[0];
    int E = in_sizes[2] / 2;
    const int* esrc = eidx;
    const int* edst = eidx + E;

    char* ws = (char*)d_ws;
    int*   cnt      = (int*)  (ws + 0x0);        // N ints
    int*   offs     = (int*)  (ws + 0x80000);    // N+1 ints
    int*   partials = (int*)  (ws + 0x100000);   // <=512 ints
    float* dinv     = (float*)(ws + 0x180000);   // N floats
    int*   csrc     = (int*)  (ws + 0x200000);   // E+N ints  (~6.8 MB)
    float* cnorm    = (float*)(ws + 0xA00000);   // E+N floats (~6.8 MB)
    float* A        = (float*)(ws + 0x1400000);  // N*128 floats (51.2 MB)
    float* B        = (float*)d_out;             // N*128 floats

    int nb = (N + 255) / 256;

    hipMemsetAsync(cnt, 0, (size_t)N * 4, stream);
    k_count<<<1024, 256, 0, stream>>>(edst, cnt, E);
    k_dinv<<<nb, 256, 0, stream>>>(cnt, dinv, N);
    k_scan_a<<<nb, 256, 0, stream>>>(cnt, offs, partials, N);
    k_scan_b<<<1, 512, 0, stream>>>(partials, nb);
    k_scan_c<<<(N + 1 + 255) / 256, 256, 0, stream>>>(offs, partials, N, nb);
    hipMemsetAsync(cnt, 0, (size_t)N * 4, stream);
    k_fill<<<1024, 256, 0, stream>>>(esrc, edst, offs, cnt, dinv, csrc, cnorm, E);
    k_fill_loops<<<nb, 256, 0, stream>>>(offs, cnt, dinv, csrc, cnorm, N);

    k_feat<<<(N + 3) / 4, 256, 0, stream>>>(label, bbox, emb, w1, b1, w2, b2, A, N);

    int gemm_grid = (N + 63) / 64;
    int agg_grid  = (N + 1) / 2;

    // layer 0: A -> gemm(A) -> agg -> B (relu)
    k_gemm128<<<gemm_grid, 256, 0, stream>>>(A, wg0, N);
    k_agg<<<agg_grid, 256, 0, stream>>>(A, offs, csrc, cnorm, bg0, B, N, 1);
    // layer 1: B -> gemm(B) -> agg -> A (relu)
    k_gemm128<<<gemm_grid, 256, 0, stream>>>(B, wg1, N);
    k_agg<<<agg_grid, 256, 0, stream>>>(B, offs, csrc, cnorm, bg1, A, N, 1);
    // layer 2: A -> gemm(A) -> agg -> B = d_out (no relu)
    k_gemm128<<<gemm_grid, 256, 0, stream>>>(A, wg2, N);
    k_agg<<<agg_grid, 256, 0, stream>>>(A, offs, csrc, cnorm, bg2, B, N, 0);
}

// Round 2
// 866.022 us; speedup vs baseline: 1.2641x; 1.2641x over previous
//
#include <hip/hip_runtime.h>
#include <hip/hip_bf16.h>
#include <cstdint>
#include <cstddef>

// ---------------- CSR build ----------------

__global__ __launch_bounds__(256) void k_count(const int* __restrict__ dst, int* __restrict__ cnt, int E) {
    int i = blockIdx.x * blockDim.x + threadIdx.x;
    int stride = gridDim.x * blockDim.x;
    for (; i < E; i += stride) atomicAdd(&cnt[dst[i]], 1);
}

// per-block exclusive scan of (cnt[i]+1), block totals to partials; also dinv = rsqrt(deg)
__global__ __launch_bounds__(256) void k_scan_a(const int* __restrict__ cnt, int* __restrict__ offs,
                                                int* __restrict__ partials, float* __restrict__ dinv, int N) {
    __shared__ int sh[256];
    int t = threadIdx.x;
    int i = blockIdx.x * 256 + t;
    int v = (i < N) ? (cnt[i] + 1) : 0;
    sh[t] = v;
    __syncthreads();
    for (int d = 1; d < 256; d <<= 1) {
        int add = (t >= d) ? sh[t - d] : 0;
        __syncthreads();
        sh[t] += add;
        __syncthreads();
    }
    if (i < N) {
        offs[i] = sh[t] - v;       // exclusive within block
        dinv[i] = rsqrtf((float)v);
    }
    if (t == 255) partials[blockIdx.x] = sh[255];
}

// single-block inclusive scan of partials (nb <= 512)
__global__ __launch_bounds__(512) void k_scan_b(int* __restrict__ partials, int nb) {
    __shared__ int sh[512];
    int t = threadIdx.x;
    int v = (t < nb) ? partials[t] : 0;
    sh[t] = v;
    __syncthreads();
    for (int d = 1; d < 512; d <<= 1) {
        int add = (t >= d) ? sh[t - d] : 0;
        __syncthreads();
        sh[t] += add;
        __syncthreads();
    }
    if (t < nb) partials[t] = sh[t];
}

__global__ __launch_bounds__(256) void k_scan_c(int* __restrict__ offs, const int* __restrict__ partials,
                                                int N, int nb) {
    int i = blockIdx.x * 256 + threadIdx.x;
    if (i < N) {
        int b = i >> 8;
        if (b > 0) offs[i] += partials[b - 1];
    } else if (i == N) {
        offs[N] = partials[nb - 1];
    }
}

__global__ __launch_bounds__(256) void k_fill(const int* __restrict__ src, const int* __restrict__ dst,
                                              const int* __restrict__ offs, int* __restrict__ cur,
                                              const float* __restrict__ dinv,
                                              int2* __restrict__ cpack, int E) {
    int i = blockIdx.x * blockDim.x + threadIdx.x;
    int stride = gridDim.x * blockDim.x;
    for (; i < E; i += stride) {
        int s = src[i], d = dst[i];
        int pos = offs[d] + atomicAdd(&cur[d], 1);
        cpack[pos] = make_int2(s, __float_as_int(dinv[s] * dinv[d]));
    }
}

__global__ __launch_bounds__(256) void k_fill_loops(const int* __restrict__ offs, int* __restrict__ cur,
                                                    const float* __restrict__ dinv,
                                                    int2* __restrict__ cpack, int N) {
    int i = blockIdx.x * blockDim.x + threadIdx.x;
    if (i < N) {
        int pos = offs[i] + atomicAdd(&cur[i], 1);
        float di = dinv[i];
        cpack[pos] = make_int2(i, __float_as_int(di * di));
    }
}

// ---------------- node features: x = [emb[label], MLP(bbox)] ----------------

__global__ __launch_bounds__(256) void k_feat(const int* __restrict__ label, const float* __restrict__ bbox,
                                              const float* __restrict__ emb,
                                              const float* __restrict__ w1, const float* __restrict__ b1,
                                              const float* __restrict__ w2, const float* __restrict__ b2,
                                              float* __restrict__ X, int N) {
    __shared__ float w1s[4 * 64];
    __shared__ float b1s[64], b2s[64];
    __shared__ float w2s[64 * 64];
    __shared__ float h1s[4][64];
    int t = threadIdx.x;
    if (t < 256) w1s[t] = w1[t];
    if (t < 64) { b1s[t] = b1[t]; b2s[t] = b2[t]; }
    for (int i = t; i < 64 * 64; i += 256) w2s[i] = w2[i];
    __syncthreads();

    int wave = t >> 6, lane = t & 63;
    int node = blockIdx.x * 4 + wave;
    bool ok = node < N;

    float h1 = 0.f;
    if (ok) {
        float bb0 = bbox[node * 4 + 0];
        float bb1 = bbox[node * 4 + 1];
        float bb2 = bbox[node * 4 + 2];
        float bb3 = bbox[node * 4 + 3];
        h1 = bb0 * w1s[0 * 64 + lane] + bb1 * w1s[1 * 64 + lane]
           + bb2 * w1s[2 * 64 + lane] + bb3 * w1s[3 * 64 + lane] + b1s[lane];
        h1 = fmaxf(h1, 0.f);
    }
    h1s[wave][lane] = h1;
    __syncthreads();

    if (ok) {
        float acc = b2s[lane];
        #pragma unroll 8
        for (int k = 0; k < 64; ++k) acc += h1s[wave][k] * w2s[k * 64 + lane];
        int lb = label[node];
        X[(size_t)node * 128 + lane] = emb[(size_t)lb * 64 + lane];
        X[(size_t)node * 128 + 64 + lane] = acc;
    }
}

// ---------------- in-place X <- X @ W  (W is 128x128 row-major) ----------------

__global__ __launch_bounds__(256) void k_gemm128(float* __restrict__ X, const float* __restrict__ W, int N) {
    __shared__ float Xl[64 * 128];   // 32 KiB: full 64-row tile
    __shared__ float Wl[64 * 128];   // 32 KiB: half of W (64 k-rows)
    int t = threadIdx.x;
    int n0 = blockIdx.x * 64;
    int rows = N - n0; if (rows > 64) rows = 64;

    const float4* X4 = (const float4*)X;
    float4* Xl4 = (float4*)Xl;
    for (int i = t; i < rows * 32; i += 256) {
        Xl4[i] = X4[(size_t)n0 * 32 + i];
    }

    float acc[4][8];
    #pragma unroll
    for (int i = 0; i < 4; ++i)
        #pragma unroll
        for (int j = 0; j < 8; ++j) acc[i][j] = 0.f;

    int tr = t >> 4;     // 0..15 -> rows tr*4 .. tr*4+3
    int tc = t & 15;     // 0..15 -> cols tc*8 .. tc*8+7
    const float4* W4 = (const float4*)W;
    float4* Wl4 = (float4*)Wl;

    for (int kp = 0; kp < 2; ++kp) {
        __syncthreads();   // Xl ready (kp=0) / previous pass done reading Wl (kp=1)
        for (int i = t; i < 64 * 32; i += 256) Wl4[i] = W4[kp * 2048 + i];
        __syncthreads();
        #pragma unroll 16
        for (int kl = 0; kl < 64; ++kl) {
            int k = kp * 64 + kl;
            float4 w0 = Wl4[kl * 32 + tc * 2];
            float4 w1 = Wl4[kl * 32 + tc * 2 + 1];
            float xv[4];
            #pragma unroll
            for (int i = 0; i < 4; ++i) xv[i] = Xl[(tr * 4 + i) * 128 + k];
            #pragma unroll
            for (int i = 0; i < 4; ++i) {
                acc[i][0] += xv[i] * w0.x; acc[i][1] += xv[i] * w0.y;
                acc[i][2] += xv[i] * w0.z; acc[i][3] += xv[i] * w0.w;
                acc[i][4] += xv[i] * w1.x; acc[i][5] += xv[i] * w1.y;
                acc[i][6] += xv[i] * w1.z; acc[i][7] += xv[i] * w1.w;
            }
        }
    }

    #pragma unroll
    for (int i = 0; i < 4; ++i) {
        int r = tr * 4 + i;
        if (r < rows) {
            float4* out = (float4*)(X + ((size_t)(n0 + r)) * 128 + tc * 8);
            out[0] = make_float4(acc[i][0], acc[i][1], acc[i][2], acc[i][3]);
            out[1] = make_float4(acc[i][4], acc[i][5], acc[i][6], acc[i][7]);
        }
    }
}

// ---------------- aggregation: Y[n] = relu?(sum_e norm_e * H[src_e] + b) ----------------
// 1 wave per node; lane owns cols {2*lane, 2*lane+1}; edge (src,norm) broadcast via shfl.

__global__ __launch_bounds__(256) void k_agg(const float2* __restrict__ H2, const int* __restrict__ offs,
                                             const int2* __restrict__ cpack,
                                             const float* __restrict__ bias, float* __restrict__ Y,
                                             int N, int do_relu) {
    int node = blockIdx.x * 4 + (threadIdx.x >> 6);
    if (node >= N) return;
    int lane = threadIdx.x & 63;
    int i0 = offs[node], i1 = offs[node + 1];

    float2 acc = make_float2(0.f, 0.f);
    for (int base = i0; base < i1; base += 64) {
        int navail = i1 - base; if (navail > 64) navail = 64;
        int li = lane < navail ? lane : (navail - 1);
        int2 ep = cpack[base + li];

        int e = 0;
        for (; e + 4 <= navail; e += 4) {
            int   s0 = __shfl(ep.x, e + 0); float w0 = __int_as_float(__shfl(ep.y, e + 0));
            int   s1 = __shfl(ep.x, e + 1); float w1 = __int_as_float(__shfl(ep.y, e + 1));
            int   s2 = __shfl(ep.x, e + 2); float w2 = __int_as_float(__shfl(ep.y, e + 2));
            int   s3 = __shfl(ep.x, e + 3); float w3 = __int_as_float(__shfl(ep.y, e + 3));
            float2 h0 = H2[(size_t)s0 * 64 + lane];
            float2 h1 = H2[(size_t)s1 * 64 + lane];
            float2 h2 = H2[(size_t)s2 * 64 + lane];
            float2 h3 = H2[(size_t)s3 * 64 + lane];
            acc.x += h0.x * w0; acc.y += h0.y * w0;
            acc.x += h1.x * w1; acc.y += h1.y * w1;
            acc.x += h2.x * w2; acc.y += h2.y * w2;
            acc.x += h3.x * w3; acc.y += h3.y * w3;
        }
        for (; e < navail; ++e) {
            int s = __shfl(ep.x, e); float w = __int_as_float(__shfl(ep.y, e));
            float2 h = H2[(size_t)s * 64 + lane];
            acc.x += h.x * w; acc.y += h.y * w;
        }
    }

    float2 b = ((const float2*)bias)[lane];
    acc.x += b.x; acc.y += b.y;
    if (do_relu) { acc.x = fmaxf(acc.x, 0.f); acc.y = fmaxf(acc.y, 0.f); }
    ((float2*)Y)[(size_t)node * 64 + lane] = acc;
}

// ---------------- launch ----------------

extern "C" void kernel_launch(void* const* d_in, const int* in_sizes, int n_in,
                              void* d_out, int out_size, void* d_ws, size_t ws_size,
                              hipStream_t stream) {
    const int*   label = (const int*)d_in[0];
    const float* bbox  = (const float*)d_in[1];
    const int*   eidx  = (const int*)d_in[2];
    const float* emb   = (const float*)d_in[3];
    const float* w1    = (const float*)d_in[4];
    const float* b1    = (const float*)d_in[5];
    const float* w2    = (const float*)d_in[6];
    const float* b2    = (const float*)d_in[7];
    const float* wg0   = (const float*)d_in[8];
    const float* bg0   = (const float*)d_in[9];
    const float* wg1   = (const float*)d_in[10];
    const float* bg1   = (const float*)d_in[11];
    const float* wg2   = (const float*)d_in[12];
    const float* bg2   = (const float*)d_in[13];

    int N = in_sizes[0];
    int E = in_sizes[2] / 2;
    const int* esrc = eidx;
    const int* edst = eidx + E;

    char* ws = (char*)d_ws;
    int*   cnt      = (int*)  (ws + 0x0);        // N ints
    int*   offs     = (int*)  (ws + 0x80000);    // N+1 ints
    int*   partials = (int*)  (ws + 0x100000);   // <=512 ints
    float* dinv     = (float*)(ws + 0x180000);   // N floats
    int2*  cpack    = (int2*) (ws + 0x200000);   // (E+N) int2 (~13.6 MB)
    float* A        = (float*)(ws + 0x1400000);  // N*128 floats (51.2 MB)
    float* B        = (float*)d_out;             // N*128 floats

    int nb = (N + 255) / 256;

    hipMemsetAsync(cnt, 0, (size_t)N * 4, stream);
    k_count<<<1024, 256, 0, stream>>>(edst, cnt, E);
    k_scan_a<<<nb, 256, 0, stream>>>(cnt, offs, partials, dinv, N);
    k_scan_b<<<1, 512, 0, stream>>>(partials, nb);
    k_scan_c<<<(N + 1 + 255) / 256, 256, 0, stream>>>(offs, partials, N, nb);
    hipMemsetAsync(cnt, 0, (size_t)N * 4, stream);
    k_fill<<<1024, 256, 0, stream>>>(esrc, edst, offs, cnt, dinv, cpack, E);
    k_fill_loops<<<nb, 256, 0, stream>>>(offs, cnt, dinv, cpack, N);

    k_feat<<<(N + 3) / 4, 256, 0, stream>>>(label, bbox, emb, w1, b1, w2, b2, A, N);

    int gemm_grid = (N + 63) / 64;
    int agg_grid  = (N + 3) / 4;

    // layer 0: A -> gemm(A) -> agg -> B (relu)
    k_gemm128<<<gemm_grid, 256, 0, stream>>>(A, wg0, N);
    k_agg<<<agg_grid, 256, 0, stream>>>((const float2*)A, offs, cpack, bg0, B, N, 1);
    // layer 1: B -> gemm(B) -> agg -> A (relu)
    k_gemm128<<<gemm_grid, 256, 0, stream>>>(B, wg1, N);
    k_agg<<<agg_grid, 256, 0, stream>>>((const float2*)B, offs, cpack, bg1, A, N, 1);
    // layer 2: A -> gemm(A) -> agg -> B = d_out (no relu)
    k_gemm128<<<gemm_grid, 256, 0, stream>>>(A, wg2, N);
    k_agg<<<agg_grid, 256, 0, stream>>>((const float2*)A, offs, cpack, bg2, B, N, 0);
}

// Round 3
// 799.145 us; speedup vs baseline: 1.3699x; 1.0837x over previous
//
#include <hip/hip_runtime.h>
#include <hip/hip_bf16.h>
#include <cstdint>
#include <cstddef>

// ---------------- CSR build ----------------

__global__ __launch_bounds__(256) void k_count(const int* __restrict__ dst, int* __restrict__ cnt, int E) {
    int i = blockIdx.x * blockDim.x + threadIdx.x;
    int stride = gridDim.x * blockDim.x;
    for (; i < E; i += stride) atomicAdd(&cnt[dst[i]], 1);
}

// per-block exclusive scan of (cnt[i]+1), block totals to partials; also dinv = rsqrt(deg)
__global__ __launch_bounds__(256) void k_scan_a(const int* __restrict__ cnt, int* __restrict__ offs,
                                                int* __restrict__ partials, float* __restrict__ dinv, int N) {
    __shared__ int sh[256];
    int t = threadIdx.x;
    int i = blockIdx.x * 256 + t;
    int v = (i < N) ? (cnt[i] + 1) : 0;
    sh[t] = v;
    __syncthreads();
    for (int d = 1; d < 256; d <<= 1) {
        int add = (t >= d) ? sh[t - d] : 0;
        __syncthreads();
        sh[t] += add;
        __syncthreads();
    }
    if (i < N) {
        offs[i] = sh[t] - v;       // exclusive within block
        dinv[i] = rsqrtf((float)v);
    }
    if (t == 255) partials[blockIdx.x] = sh[255];
}

// single-block inclusive scan of partials (nb <= 512)
__global__ __launch_bounds__(512) void k_scan_b(int* __restrict__ partials, int nb) {
    __shared__ int sh[512];
    int t = threadIdx.x;
    int v = (t < nb) ? partials[t] : 0;
    sh[t] = v;
    __syncthreads();
    for (int d = 1; d < 512; d <<= 1) {
        int add = (t >= d) ? sh[t - d] : 0;
        __syncthreads();
        sh[t] += add;
        __syncthreads();
    }
    if (t < nb) partials[t] = sh[t];
}

__global__ __launch_bounds__(256) void k_scan_c(int* __restrict__ offs, const int* __restrict__ partials,
                                                int N, int nb) {
    int i = blockIdx.x * 256 + threadIdx.x;
    if (i < N) {
        int b = i >> 8;
        if (b > 0) offs[i] += partials[b - 1];
    } else if (i == N) {
        offs[N] = partials[nb - 1];
    }
}

__global__ __launch_bounds__(256) void k_fill(const int* __restrict__ src, const int* __restrict__ dst,
                                              const int* __restrict__ offs, int* __restrict__ cur,
                                              const float* __restrict__ dinv,
                                              int2* __restrict__ cpack, int E) {
    int i = blockIdx.x * blockDim.x + threadIdx.x;
    int stride = gridDim.x * blockDim.x;
    for (; i < E; i += stride) {
        int s = src[i], d = dst[i];
        int pos = offs[d] + atomicAdd(&cur[d], 1);
        cpack[pos] = make_int2(s, __float_as_int(dinv[s] * dinv[d]));
    }
}

__global__ __launch_bounds__(256) void k_fill_loops(const int* __restrict__ offs, int* __restrict__ cur,
                                                    const float* __restrict__ dinv,
                                                    int2* __restrict__ cpack, int N) {
    int i = blockIdx.x * blockDim.x + threadIdx.x;
    if (i < N) {
        int pos = offs[i] + atomicAdd(&cur[i], 1);
        float di = dinv[i];
        cpack[pos] = make_int2(i, __float_as_int(di * di));
    }
}

// ---------------- node features: x = [emb[label], MLP(bbox)] ----------------

__global__ __launch_bounds__(256) void k_feat(const int* __restrict__ label, const float* __restrict__ bbox,
                                              const float* __restrict__ emb,
                                              const float* __restrict__ w1, const float* __restrict__ b1,
                                              const float* __restrict__ w2, const float* __restrict__ b2,
                                              float* __restrict__ X, int N) {
    __shared__ float w1s[4 * 64];
    __shared__ float b1s[64], b2s[64];
    __shared__ float w2s[64 * 64];
    __shared__ float h1s[4][64];
    int t = threadIdx.x;
    if (t < 256) w1s[t] = w1[t];
    if (t < 64) { b1s[t] = b1[t]; b2s[t] = b2[t]; }
    for (int i = t; i < 64 * 64; i += 256) w2s[i] = w2[i];
    __syncthreads();

    int wave = t >> 6, lane = t & 63;
    int node = blockIdx.x * 4 + wave;
    bool ok = node < N;

    float h1 = 0.f;
    if (ok) {
        float bb0 = bbox[node * 4 + 0];
        float bb1 = bbox[node * 4 + 1];
        float bb2 = bbox[node * 4 + 2];
        float bb3 = bbox[node * 4 + 3];
        h1 = bb0 * w1s[0 * 64 + lane] + bb1 * w1s[1 * 64 + lane]
           + bb2 * w1s[2 * 64 + lane] + bb3 * w1s[3 * 64 + lane] + b1s[lane];
        h1 = fmaxf(h1, 0.f);
    }
    h1s[wave][lane] = h1;
    __syncthreads();

    if (ok) {
        float acc = b2s[lane];
        #pragma unroll 8
        for (int k = 0; k < 64; ++k) acc += h1s[wave][k] * w2s[k * 64 + lane];
        int lb = label[node];
        X[(size_t)node * 128 + lane] = emb[(size_t)lb * 64 + lane];
        X[(size_t)node * 128 + 64 + lane] = acc;
    }
}

// ---------------- fused layer: Y = relu?( (A_hat @ X) @ W + b ) ----------------
// Block = 256 threads = 4 waves = 32 nodes (8 per wave).
// Phase 1: gather-aggregate Z rows into LDS (lane owns cols {2l,2l+1}, unroll-8 loads).
// Phase 2: block GEMM Z[32][128] @ W[128][128] with W staged in 16KB chunks, bias+relu, store.

__global__ __launch_bounds__(256) void k_agg_gemm(const float2* __restrict__ X2, const int* __restrict__ offs,
                                                  const int2* __restrict__ cpack,
                                                  const float* __restrict__ W, const float* __restrict__ bias,
                                                  float* __restrict__ Y, int N, int do_relu) {
    __shared__ float Zl[32][132];   // padded: bank = (4*row + k) % 32
    __shared__ float Wl[32 * 128];  // one 32-k-row chunk of W

    int t = threadIdx.x;
    int wave = t >> 6, lane = t & 63;
    int nodeBase = blockIdx.x * 32 + wave * 8;

    // ---- phase 1: aggregate 8 nodes per wave ----
    for (int nn = 0; nn < 8; ++nn) {
        int node = nodeBase + nn;
        float2 acc = make_float2(0.f, 0.f);
        if (node < N) {
            int i0 = offs[node], i1 = offs[node + 1];
            for (int base = i0; base < i1; base += 64) {
                int navail = i1 - base; if (navail > 64) navail = 64;
                int li = lane < navail ? lane : (navail - 1);
                int2 ep = cpack[base + li];
                int e = 0;
                for (; e + 8 <= navail; e += 8) {
                    int s[8]; float w[8];
                    #pragma unroll
                    for (int j = 0; j < 8; ++j) {
                        s[j] = __shfl(ep.x, e + j);
                        w[j] = __int_as_float(__shfl(ep.y, e + j));
                    }
                    float2 h[8];
                    #pragma unroll
                    for (int j = 0; j < 8; ++j) h[j] = X2[(size_t)s[j] * 64 + lane];
                    #pragma unroll
                    for (int j = 0; j < 8; ++j) { acc.x += h[j].x * w[j]; acc.y += h[j].y * w[j]; }
                }
                for (; e < navail; ++e) {
                    int s0 = __shfl(ep.x, e); float w0 = __int_as_float(__shfl(ep.y, e));
                    float2 h = X2[(size_t)s0 * 64 + lane];
                    acc.x += h.x * w0; acc.y += h.y * w0;
                }
            }
        }
        *(float2*)&Zl[wave * 8 + nn][2 * lane] = acc;
    }

    __syncthreads();   // Zl complete

    // ---- phase 2: Y[32][128] = Zl @ W, micro-tile 2 rows x 8 cols per thread ----
    int rowg = t >> 4;   // 0..15 -> rows rowg*2, rowg*2+1
    int colg = t & 15;   // 0..15 -> cols colg*8 .. +7
    float a0[8], a1[8];
    #pragma unroll
    for (int j = 0; j < 8; ++j) { a0[j] = 0.f; a1[j] = 0.f; }

    for (int kc = 0; kc < 4; ++kc) {
        if (kc) __syncthreads();   // previous chunk fully consumed
        for (int i = t; i < 32 * 32; i += 256) ((float4*)Wl)[i] = ((const float4*)W)[kc * 1024 + i];
        __syncthreads();
        #pragma unroll
        for (int kk = 0; kk < 32; ++kk) {
            float z0 = Zl[rowg * 2 + 0][kc * 32 + kk];
            float z1 = Zl[rowg * 2 + 1][kc * 32 + kk];
            float4 w0 = *(const float4*)&Wl[kk * 128 + colg * 8];
            float4 w1 = *(const float4*)&Wl[kk * 128 + colg * 8 + 4];
            a0[0] += z0 * w0.x; a0[1] += z0 * w0.y; a0[2] += z0 * w0.z; a0[3] += z0 * w0.w;
            a0[4] += z0 * w1.x; a0[5] += z0 * w1.y; a0[6] += z0 * w1.z; a0[7] += z0 * w1.w;
            a1[0] += z1 * w0.x; a1[1] += z1 * w0.y; a1[2] += z1 * w0.z; a1[3] += z1 * w0.w;
            a1[4] += z1 * w1.x; a1[5] += z1 * w1.y; a1[6] += z1 * w1.z; a1[7] += z1 * w1.w;
        }
    }

    float4 bv0 = *(const float4*)&bias[colg * 8];
    float4 bv1 = *(const float4*)&bias[colg * 8 + 4];
    a0[0] += bv0.x; a0[1] += bv0.y; a0[2] += bv0.z; a0[3] += bv0.w;
    a0[4] += bv1.x; a0[5] += bv1.y; a0[6] += bv1.z; a0[7] += bv1.w;
    a1[0] += bv0.x; a1[1] += bv0.y; a1[2] += bv0.z; a1[3] += bv0.w;
    a1[4] += bv1.x; a1[5] += bv1.y; a1[6] += bv1.z; a1[7] += bv1.w;
    if (do_relu) {
        #pragma unroll
        for (int j = 0; j < 8; ++j) { a0[j] = fmaxf(a0[j], 0.f); a1[j] = fmaxf(a1[j], 0.f); }
    }

    int node0 = blockIdx.x * 32 + rowg * 2;
    if (node0 < N) {
        float4* out = (float4*)(Y + (size_t)node0 * 128 + colg * 8);
        out[0] = make_float4(a0[0], a0[1], a0[2], a0[3]);
        out[1] = make_float4(a0[4], a0[5], a0[6], a0[7]);
    }
    if (node0 + 1 < N) {
        float4* out = (float4*)(Y + (size_t)(node0 + 1) * 128 + colg * 8);
        out[0] = make_float4(a1[0], a1[1], a1[2], a1[3]);
        out[1] = make_float4(a1[4], a1[5], a1[6], a1[7]);
    }
}

// ---------------- launch ----------------

extern "C" void kernel_launch(void* const* d_in, const int* in_sizes, int n_in,
                              void* d_out, int out_size, void* d_ws, size_t ws_size,
                              hipStream_t stream) {
    const int*   label = (const int*)d_in[0];
    const float* bbox  = (const float*)d_in[1];
    const int*   eidx  = (const int*)d_in[2];
    const float* emb   = (const float*)d_in[3];
    const float* w1    = (const float*)d_in[4];
    const float* b1    = (const float*)d_in[5];
    const float* w2    = (const float*)d_in[6];
    const float* b2    = (const float*)d_in[7];
    const float* wg0   = (const float*)d_in[8];
    const float* bg0   = (const float*)d_in[9];
    const float* wg1   = (const float*)d_in[10];
    const float* bg1   = (const float*)d_in[11];
    const float* wg2   = (const float*)d_in[12];
    const float* bg2   = (const float*)d_in[13];

    int N = in_sizes[0];
    int E = in_sizes[2] / 2;
    const int* esrc = eidx;
    const int* edst = eidx + E;

    char* ws = (char*)d_ws;
    int*   cnt      = (int*)  (ws + 0x0);        // N ints
    int*   offs     = (int*)  (ws + 0x80000);    // N+1 ints
    int*   partials = (int*)  (ws + 0x100000);   // <=512 ints
    float* dinv     = (float*)(ws + 0x180000);   // N floats
    int2*  cpack    = (int2*) (ws + 0x200000);   // (E+N) int2 (~13.6 MB)
    float* A        = (float*)(ws + 0x1400000);  // N*128 floats (51.2 MB)
    float* B        = (float*)d_out;             // N*128 floats

    int nb = (N + 255) / 256;

    hipMemsetAsync(cnt, 0, (size_t)N * 4, stream);
    k_count<<<1024, 256, 0, stream>>>(edst, cnt, E);
    k_scan_a<<<nb, 256, 0, stream>>>(cnt, offs, partials, dinv, N);
    k_scan_b<<<1, 512, 0, stream>>>(partials, nb);
    k_scan_c<<<(N + 1 + 255) / 256, 256, 0, stream>>>(offs, partials, N, nb);
    hipMemsetAsync(cnt, 0, (size_t)N * 4, stream);
    k_fill<<<1024, 256, 0, stream>>>(esrc, edst, offs, cnt, dinv, cpack, E);
    k_fill_loops<<<nb, 256, 0, stream>>>(offs, cnt, dinv, cpack, N);

    k_feat<<<(N + 3) / 4, 256, 0, stream>>>(label, bbox, emb, w1, b1, w2, b2, A, N);

    int fuse_grid = (N + 31) / 32;

    // layer 0: B = relu( agg(A) @ W0 + b0 )
    k_agg_gemm<<<fuse_grid, 256, 0, stream>>>((const float2*)A, offs, cpack, wg0, bg0, B, N, 1);
    // layer 1: A = relu( agg(B) @ W1 + b1 )
    k_agg_gemm<<<fuse_grid, 256, 0, stream>>>((const float2*)B, offs, cpack, wg1, bg1, A, N, 1);
    // layer 2: d_out = agg(A) @ W2 + b2
    k_agg_gemm<<<fuse_grid, 256, 0, stream>>>((const float2*)A, offs, cpack, wg2, bg2, B, N, 0);
}

// Round 4
// 630.390 us; speedup vs baseline: 1.7367x; 1.2677x over previous
//
#include <hip/hip_runtime.h>
#include <hip/hip_bf16.h>
#include <hip/hip_fp16.h>
#include <cstdint>
#include <cstddef>

// ---------------- CSR build ----------------

__global__ __launch_bounds__(256) void k_count(const int* __restrict__ dst, int* __restrict__ cnt, int E) {
    int i = blockIdx.x * blockDim.x + threadIdx.x;
    int stride = gridDim.x * blockDim.x;
    for (; i < E; i += stride) atomicAdd(&cnt[dst[i]], 1);
}

// per-block exclusive scan of (cnt[i]+1), block totals to partials; also dinv = rsqrt(deg)
__global__ __launch_bounds__(256) void k_scan_a(const int* __restrict__ cnt, int* __restrict__ offs,
                                                int* __restrict__ partials, float* __restrict__ dinv, int N) {
    __shared__ int sh[256];
    int t = threadIdx.x;
    int i = blockIdx.x * 256 + t;
    int v = (i < N) ? (cnt[i] + 1) : 0;
    sh[t] = v;
    __syncthreads();
    for (int d = 1; d < 256; d <<= 1) {
        int add = (t >= d) ? sh[t - d] : 0;
        __syncthreads();
        sh[t] += add;
        __syncthreads();
    }
    if (i < N) {
        offs[i] = sh[t] - v;       // exclusive within block
        dinv[i] = rsqrtf((float)v);
    }
    if (t == 255) partials[blockIdx.x] = sh[255];
}

// single-block inclusive scan of partials (nb <= 512)
__global__ __launch_bounds__(512) void k_scan_b(int* __restrict__ partials, int nb) {
    __shared__ int sh[512];
    int t = threadIdx.x;
    int v = (t < nb) ? partials[t] : 0;
    sh[t] = v;
    __syncthreads();
    for (int d = 1; d < 512; d <<= 1) {
        int add = (t >= d) ? sh[t - d] : 0;
        __syncthreads();
        sh[t] += add;
        __syncthreads();
    }
    if (t < nb) partials[t] = sh[t];
}

__global__ __launch_bounds__(256) void k_scan_c(int* __restrict__ offs, const int* __restrict__ partials,
                                                int N, int nb) {
    int i = blockIdx.x * 256 + threadIdx.x;
    if (i < N) {
        int b = i >> 8;
        if (b > 0) offs[i] += partials[b - 1];
    } else if (i == N) {
        offs[N] = partials[nb - 1];
    }
}

__global__ __launch_bounds__(256) void k_fill(const int* __restrict__ src, const int* __restrict__ dst,
                                              const int* __restrict__ offs, int* __restrict__ cur,
                                              const float* __restrict__ dinv,
                                              int2* __restrict__ cpack, int E) {
    int i = blockIdx.x * blockDim.x + threadIdx.x;
    int stride = gridDim.x * blockDim.x;
    for (; i < E; i += stride) {
        int s = src[i], d = dst[i];
        int pos = offs[d] + atomicAdd(&cur[d], 1);
        cpack[pos] = make_int2(s, __float_as_int(dinv[s] * dinv[d]));
    }
}

__global__ __launch_bounds__(256) void k_fill_loops(const int* __restrict__ offs, int* __restrict__ cur,
                                                    const float* __restrict__ dinv,
                                                    int2* __restrict__ cpack, int N) {
    int i = blockIdx.x * blockDim.x + threadIdx.x;
    if (i < N) {
        int pos = offs[i] + atomicAdd(&cur[i], 1);
        float di = dinv[i];
        cpack[pos] = make_int2(i, __float_as_int(di * di));
    }
}

// ---------------- node features: x = [emb[label], MLP(bbox)] -> fp16 ----------------

__global__ __launch_bounds__(256) void k_feat(const int* __restrict__ label, const float* __restrict__ bbox,
                                              const float* __restrict__ emb,
                                              const float* __restrict__ w1, const float* __restrict__ b1,
                                              const float* __restrict__ w2, const float* __restrict__ b2,
                                              __half* __restrict__ X, int N) {
    __shared__ float w1s[4 * 64];
    __shared__ float b1s[64], b2s[64];
    __shared__ float w2s[64 * 64];
    __shared__ float h1s[4][64];
    int t = threadIdx.x;
    if (t < 256) w1s[t] = w1[t];
    if (t < 64) { b1s[t] = b1[t]; b2s[t] = b2[t]; }
    for (int i = t; i < 64 * 64; i += 256) w2s[i] = w2[i];
    __syncthreads();

    int wave = t >> 6, lane = t & 63;
    int node = blockIdx.x * 4 + wave;
    bool ok = node < N;

    float h1 = 0.f;
    if (ok) {
        float bb0 = bbox[node * 4 + 0];
        float bb1 = bbox[node * 4 + 1];
        float bb2 = bbox[node * 4 + 2];
        float bb3 = bbox[node * 4 + 3];
        h1 = bb0 * w1s[0 * 64 + lane] + bb1 * w1s[1 * 64 + lane]
           + bb2 * w1s[2 * 64 + lane] + bb3 * w1s[3 * 64 + lane] + b1s[lane];
        h1 = fmaxf(h1, 0.f);
    }
    h1s[wave][lane] = h1;
    __syncthreads();

    if (ok) {
        float acc = b2s[lane];
        #pragma unroll 8
        for (int k = 0; k < 64; ++k) acc += h1s[wave][k] * w2s[k * 64 + lane];
        int lb = label[node];
        X[(size_t)node * 128 + lane] = __float2half(emb[(size_t)lb * 64 + lane]);
        X[(size_t)node * 128 + 64 + lane] = __float2half(acc);
    }
}

// ---------------- fused layer: Y = relu?( (A_hat @ X) @ W + b ) ----------------
// X is fp16 [N][128]. Block = 256 threads = 4 waves = 32 nodes (8 per wave).
// Phase 1: gather-aggregate (fp32 acc) into Zl[32][132] LDS.
// Phase 2: Zl @ W with W read directly from global (L1/L2 broadcast), bias+relu,
//          output fp16 (intermediate layers) or fp32 (final).

template <int OUT_HALF>
__global__ __launch_bounds__(256) void k_agg_gemm(const __half2* __restrict__ X2, const int* __restrict__ offs,
                                                  const int2* __restrict__ cpack,
                                                  const float* __restrict__ W, const float* __restrict__ bias,
                                                  void* __restrict__ Yv, int N, int do_relu) {
    __shared__ float Zl[32][132];   // row stride 132: 16B-aligned rows, bank base 4r%32 -> conflict-free

    int t = threadIdx.x;
    int wave = t >> 6, lane = t & 63;
    int nodeBase = blockIdx.x * 32 + wave * 8;

    // ---- phase 1: aggregate 8 nodes per wave; lane owns cols {2l, 2l+1} ----
    for (int nn = 0; nn < 8; ++nn) {
        int node = nodeBase + nn;
        float2 acc = make_float2(0.f, 0.f);
        if (node < N) {
            int i0 = offs[node], i1 = offs[node + 1];
            for (int base = i0; base < i1; base += 64) {
                int navail = i1 - base; if (navail > 64) navail = 64;
                int li = lane < navail ? lane : (navail - 1);
                int2 ep = cpack[base + li];
                for (int e = 0; e < navail; e += 8) {
                    int s[8]; float w[8];
                    #pragma unroll
                    for (int j = 0; j < 8; ++j) {
                        int idx = e + j;
                        int cl = idx < navail ? idx : (navail - 1);
                        s[j] = __shfl(ep.x, cl);
                        float wj = __int_as_float(__shfl(ep.y, cl));
                        w[j] = idx < navail ? wj : 0.f;
                    }
                    __half2 h[8];
                    #pragma unroll
                    for (int j = 0; j < 8; ++j) h[j] = X2[(size_t)s[j] * 64 + lane];
                    #pragma unroll
                    for (int j = 0; j < 8; ++j) {
                        float2 f = __half22float2(h[j]);
                        acc.x += f.x * w[j];
                        acc.y += f.y * w[j];
                    }
                }
            }
        }
        *(float2*)&Zl[wave * 8 + nn][2 * lane] = acc;
    }

    __syncthreads();   // Zl complete

    // ---- phase 2: Y[32][128] = Zl @ W; thread = 2 rows x 8 cols ----
    int rowg = t >> 4;   // rows 2*rowg, 2*rowg+1
    int colg = t & 15;   // cols colg*8 .. +7
    float a0[8], a1[8];
    #pragma unroll
    for (int j = 0; j < 8; ++j) { a0[j] = 0.f; a1[j] = 0.f; }

    const float* Zr0 = &Zl[rowg * 2 + 0][0];
    const float* Zr1 = &Zl[rowg * 2 + 1][0];

    #pragma unroll 4
    for (int k0 = 0; k0 < 128; k0 += 4) {
        float4 z0 = *(const float4*)&Zr0[k0];
        float4 z1 = *(const float4*)&Zr1[k0];
        #pragma unroll
        for (int j = 0; j < 4; ++j) {
            int k = k0 + j;
            float zz0 = j == 0 ? z0.x : j == 1 ? z0.y : j == 2 ? z0.z : z0.w;
            float zz1 = j == 0 ? z1.x : j == 1 ? z1.y : j == 2 ? z1.z : z1.w;
            float4 w0 = *(const float4*)&W[k * 128 + colg * 8];
            float4 w1 = *(const float4*)&W[k * 128 + colg * 8 + 4];
            a0[0] += zz0 * w0.x; a0[1] += zz0 * w0.y; a0[2] += zz0 * w0.z; a0[3] += zz0 * w0.w;
            a0[4] += zz0 * w1.x; a0[5] += zz0 * w1.y; a0[6] += zz0 * w1.z; a0[7] += zz0 * w1.w;
            a1[0] += zz1 * w0.x; a1[1] += zz1 * w0.y; a1[2] += zz1 * w0.z; a1[3] += zz1 * w0.w;
            a1[4] += zz1 * w1.x; a1[5] += zz1 * w1.y; a1[6] += zz1 * w1.z; a1[7] += zz1 * w1.w;
        }
    }

    float4 bv0 = *(const float4*)&bias[colg * 8];
    float4 bv1 = *(const float4*)&bias[colg * 8 + 4];
    a0[0] += bv0.x; a0[1] += bv0.y; a0[2] += bv0.z; a0[3] += bv0.w;
    a0[4] += bv1.x; a0[5] += bv1.y; a0[6] += bv1.z; a0[7] += bv1.w;
    a1[0] += bv0.x; a1[1] += bv0.y; a1[2] += bv0.z; a1[3] += bv0.w;
    a1[4] += bv1.x; a1[5] += bv1.y; a1[6] += bv1.z; a1[7] += bv1.w;
    if (do_relu) {
        #pragma unroll
        for (int j = 0; j < 8; ++j) { a0[j] = fmaxf(a0[j], 0.f); a1[j] = fmaxf(a1[j], 0.f); }
    }

    int node0 = blockIdx.x * 32 + rowg * 2;
    if (OUT_HALF) {
        __half* Yh = (__half*)Yv;
        if (node0 < N) {
            __half2 p0 = __float22half2_rn(make_float2(a0[0], a0[1]));
            __half2 p1 = __float22half2_rn(make_float2(a0[2], a0[3]));
            __half2 p2 = __float22half2_rn(make_float2(a0[4], a0[5]));
            __half2 p3 = __float22half2_rn(make_float2(a0[6], a0[7]));
            uint4 pk;
            pk.x = *(unsigned int*)&p0; pk.y = *(unsigned int*)&p1;
            pk.z = *(unsigned int*)&p2; pk.w = *(unsigned int*)&p3;
            *(uint4*)(Yh + (size_t)node0 * 128 + colg * 8) = pk;
        }
        if (node0 + 1 < N) {
            __half2 p0 = __float22half2_rn(make_float2(a1[0], a1[1]));
            __half2 p1 = __float22half2_rn(make_float2(a1[2], a1[3]));
            __half2 p2 = __float22half2_rn(make_float2(a1[4], a1[5]));
            __half2 p3 = __float22half2_rn(make_float2(a1[6], a1[7]));
            uint4 pk;
            pk.x = *(unsigned int*)&p0; pk.y = *(unsigned int*)&p1;
            pk.z = *(unsigned int*)&p2; pk.w = *(unsigned int*)&p3;
            *(uint4*)(Yh + (size_t)(node0 + 1) * 128 + colg * 8) = pk;
        }
    } else {
        float* Yf = (float*)Yv;
        if (node0 < N) {
            float4* out = (float4*)(Yf + (size_t)node0 * 128 + colg * 8);
            out[0] = make_float4(a0[0], a0[1], a0[2], a0[3]);
            out[1] = make_float4(a0[4], a0[5], a0[6], a0[7]);
        }
        if (node0 + 1 < N) {
            float4* out = (float4*)(Yf + (size_t)(node0 + 1) * 128 + colg * 8);
            out[0] = make_float4(a1[0], a1[1], a1[2], a1[3]);
            out[1] = make_float4(a1[4], a1[5], a1[6], a1[7]);
        }
    }
}

// ---------------- launch ----------------

extern "C" void kernel_launch(void* const* d_in, const int* in_sizes, int n_in,
                              void* d_out, int out_size, void* d_ws, size_t ws_size,
                              hipStream_t stream) {
    const int*   label = (const int*)d_in[0];
    const float* bbox  = (const float*)d_in[1];
    const int*   eidx  = (const int*)d_in[2];
    const float* emb   = (const float*)d_in[3];
    const float* w1    = (const float*)d_in[4];
    const float* b1    = (const float*)d_in[5];
    const float* w2    = (const float*)d_in[6];
    const float* b2    = (const float*)d_in[7];
    const float* wg0   = (const float*)d_in[8];
    const float* bg0   = (const float*)d_in[9];
    const float* wg1   = (const float*)d_in[10];
    const float* bg1   = (const float*)d_in[11];
    const float* wg2   = (const float*)d_in[12];
    const float* bg2   = (const float*)d_in[13];

    int N = in_sizes[0];
    int E = in_sizes[2] / 2;
    const int* esrc = eidx;
    const int* edst = eidx + E;

    char* ws = (char*)d_ws;
    int*    cnt      = (int*)   (ws + 0x0);        // N ints (400 KB)
    int*    offs     = (int*)   (ws + 0x80000);    // N+1 ints
    int*    partials = (int*)   (ws + 0x100000);   // <=512 ints
    float*  dinv     = (float*) (ws + 0x180000);   // N floats
    int2*   cpack    = (int2*)  (ws + 0x200000);   // (E+N) int2 (~13.6 MB)
    __half* Ah       = (__half*)(ws + 0x1000000);  // N*128 halves (25.6 MB)
    __half* Bh       = (__half*)(ws + 0x2900000);  // N*128 halves (25.6 MB)
    float*  Of       = (float*) d_out;             // N*128 floats

    int nb = (N + 255) / 256;

    hipMemsetAsync(cnt, 0, (size_t)N * 4, stream);
    k_count<<<1024, 256, 0, stream>>>(edst, cnt, E);
    k_scan_a<<<nb, 256, 0, stream>>>(cnt, offs, partials, dinv, N);
    k_scan_b<<<1, 512, 0, stream>>>(partials, nb);
    k_scan_c<<<(N + 1 + 255) / 256, 256, 0, stream>>>(offs, partials, N, nb);
    hipMemsetAsync(cnt, 0, (size_t)N * 4, stream);
    k_fill<<<1024, 256, 0, stream>>>(esrc, edst, offs, cnt, dinv, cpack, E);
    k_fill_loops<<<nb, 256, 0, stream>>>(offs, cnt, dinv, cpack, N);

    k_feat<<<(N + 3) / 4, 256, 0, stream>>>(label, bbox, emb, w1, b1, w2, b2, Ah, N);

    int fuse_grid = (N + 31) / 32;

    // layer 0: Bh = relu( agg(Ah) @ W0 + b0 )   (fp16 out)
    k_agg_gemm<1><<<fuse_grid, 256, 0, stream>>>((const __half2*)Ah, offs, cpack, wg0, bg0, Bh, N, 1);
    // layer 1: Ah = relu( agg(Bh) @ W1 + b1 )   (fp16 out)
    k_agg_gemm<1><<<fuse_grid, 256, 0, stream>>>((const __half2*)Bh, offs, cpack, wg1, bg1, Ah, N, 1);
    // layer 2: d_out = agg(Ah) @ W2 + b2        (fp32 out)
    k_agg_gemm<0><<<fuse_grid, 256, 0, stream>>>((const __half2*)Ah, offs, cpack, wg2, bg2, Of, N, 0);
}